// Round 5
// baseline (1078.602 us; speedup 1.0000x reference)
//
#include <hip/hip_runtime.h>
#include <cstdint>
#include <cstddef>

#define BATCH 256
#define SEQ   512
#define HID   512
#define VOCAB 128

#define BT     16              // batch rows per block (= MFMA N dim after operand swap)
#define HSTRB  528             // h-buffer row stride in BYTES (512 + 16)

typedef __attribute__((ext_vector_type(4))) int   i32x4;
typedef __attribute__((ext_vector_type(4))) float f32x4;

// tanh(z) = 1 - 2/(e^{2z}+1); saturates correctly at +/-inf
static __device__ __forceinline__ float fast_tanh(float z) {
  float e = __expf(2.f * z);
  return 1.f - 2.f * __builtin_amdgcn_rcpf(e + 1.f);
}

// ---- abs-max reduction (for quantization scales) ----
__global__ void maxred_kernel(const float* __restrict__ src, int n,
                              unsigned int* __restrict__ dst) {
  float m = 0.f;
  for (int i = blockIdx.x * blockDim.x + threadIdx.x; i < n; i += gridDim.x * blockDim.x)
    m = fmaxf(m, fabsf(src[i]));
#pragma unroll
  for (int off = 32; off; off >>= 1)
    m = fmaxf(m, __shfl_down(m, off));
  if ((threadIdx.x & 63) == 0) atomicMax(dst, __float_as_uint(m));
}

// E[v][j] = sum_k emb[v][k]*W_ih[k][j] + b_ih[j] + b_hh[j]   (plain, no LUT bake)
__global__ __launch_bounds__(512) void eproj_kernel(const float* __restrict__ emb,
                                                    const float* __restrict__ W_ih,
                                                    const float* __restrict__ b_ih,
                                                    const float* __restrict__ b_hh,
                                                    float* __restrict__ E) {
  __shared__ float es[8][64];
  const int j = threadIdx.x;
  const int v0 = blockIdx.x * 8;
  float acc[8];
#pragma unroll
  for (int v = 0; v < 8; ++v) acc[v] = 0.f;
  for (int k0 = 0; k0 < HID; k0 += 64) {
    __syncthreads();
    es[j >> 6][j & 63] = emb[(size_t)(v0 + (j >> 6)) * HID + k0 + (j & 63)];
    __syncthreads();
#pragma unroll 8
    for (int kk = 0; kk < 64; ++kk) {
      const float w = W_ih[(size_t)(k0 + kk) * HID + j];
#pragma unroll
      for (int v = 0; v < 8; ++v) acc[v] += es[v][kk] * w;
    }
  }
  const float bias = b_ih[j] + b_hh[j];
#pragma unroll
  for (int v = 0; v < 8; ++v)
    E[(size_t)(v0 + v) * HID + j] = acc[v] + bias;
}

// Pack [W_hh | W_ho] (512 x 640) into i8 MFMA fragments for 16x16x64.
// Fragment f = nt*8+kt8: lane l holds 16 i8 = W[k = kt8*64 + (l>>4)*16 + i][n = nt*16 + (l&15)]
// (A and B fragment layouts are mirrored, so the same bytes serve as the A operand
//  with m = l&15 — used that way in rnn_kernel after the operand swap.)
__global__ void pack8_kernel(const float* __restrict__ W_hh,
                             const float* __restrict__ W_ho,
                             const float* __restrict__ sc,   // sc[0]=max|W_hh|, sc[1]=max|W_ho|
                             uint4* __restrict__ Wf8) {
  const int f = blockIdx.x;            // 0..319 (40 nt * 8 kt8)
  const int nt = f >> 3, kt8 = f & 7;
  const int lane = threadIdx.x;
  const int q = lane >> 4, nn = lane & 15;
  const int n = nt * 16 + nn;
  const float inv = 127.f / ((nt < 32) ? sc[0] : sc[1]);
  union { int8_t b[16]; uint4 u; } val;
#pragma unroll
  for (int i = 0; i < 16; ++i) {
    const int k = kt8 * 64 + q * 16 + i;
    const float w = (n < HID) ? W_hh[(size_t)k * HID + n]
                              : W_ho[(size_t)k * VOCAB + (n - HID)];
    val.b[i] = (int8_t)__float2int_rn(w * inv);
  }
  Wf8[(size_t)f * 64 + lane] = val.u;
}

// Recurrence: h_t = tanh(E[x_t] + h_{t-1} @ W_hh), i8 MFMA with SWAPPED operands:
// D = W_frag (A) x h_frag (B)  =>  D row = hidden col, D col = batch row.
// Thread (wave,q,nn) owns batch row nn and 4 CONSECUTIVE hidden cols per j-tile
// => packed ds_write_b32 (2-way banks, free), float4 E-loads, float4 y-stores.
// tanh is ARITHMETIC (exp+rcp, per-lane pipelined) — the r2/r4 LDS-LUT loaded the
// per-CU LDS pipe (which also carries the K-loop A-reads) and regressed; VALU/trans
// have headroom. hbuf double-buffered => ONE barrier per step. Y fused (W_ho in AGPRs).
__global__ __launch_bounds__(512, 2)
void rnn_kernel(const int* __restrict__ x,
                const float* __restrict__ E,
                const uint4* __restrict__ Wf8,
                const float* __restrict__ sc,
                const float* __restrict__ b_o,
                float* __restrict__ out,
                float* __restrict__ outH) {
  __shared__ __align__(16) int8_t hbuf[2][BT][HSTRB];  // 16.9 KB double-buffered

  const int tid = threadIdx.x;
  const int wave = tid >> 6, lane = tid & 63;
  const int q = lane >> 4, nn = lane & 15;
  const int r0 = blockIdx.x * BT;
  const int b = r0 + nn;                 // this thread's batch row
  const float fq = sc[0] * (1.f / (127.f * 127.f));   // acc -> pre-activation scale
  const float fy = sc[1] * (1.f / (127.f * 127.f));
  const f32x4 bo4 = *(const f32x4*)&b_o[wave * 16 + q * 4];

  // 5 weight strips per wave: h-tiles nt=wave*4+j (j<2 AGPR, j>=2 VGPR) + y-tile nt=32+wave (AGPR)
  i32x4 wa[2][8], wv[2][8], wy[8];
  {
    const uint4* wb = Wf8 + lane;
#pragma unroll
    for (int j = 0; j < 2; ++j)
#pragma unroll
      for (int kt = 0; kt < 8; ++kt)
        wa[j][kt] = __builtin_bit_cast(i32x4, wb[(size_t)((wave * 4 + j) * 8 + kt) * 64]);
#pragma unroll
    for (int j = 0; j < 2; ++j)
#pragma unroll
      for (int kt = 0; kt < 8; ++kt)
        wv[j][kt] = __builtin_bit_cast(i32x4, wb[(size_t)((wave * 4 + 2 + j) * 8 + kt) * 64]);
#pragma unroll
    for (int kt = 0; kt < 8; ++kt)
      wy[kt] = __builtin_bit_cast(i32x4, wb[(size_t)((32 + wave) * 8 + kt) * 64]);
  }
#pragma unroll
  for (int j = 0; j < 2; ++j)
#pragma unroll
    for (int kt = 0; kt < 8; ++kt)
      asm volatile("" : "+a"(wa[j][kt]));
#pragma unroll
  for (int j = 0; j < 2; ++j)
#pragma unroll
    for (int kt = 0; kt < 8; ++kt)
      asm volatile("" : "+v"(wv[j][kt]));
#pragma unroll
  for (int kt = 0; kt < 8; ++kt)
    asm volatile("" : "+a"(wy[kt]));

  int tokc = x[(size_t)b * SEQ + 0];     // token prefetch for t=0 (one per thread)
  int cur = 0;

  for (int t = 0; t < SEQ; ++t) {
    const int tn = (t + 1 < SEQ) ? t + 1 : t;
    const int tokn = x[(size_t)b * SEQ + tn];

    // E slices: 4 x float4 (cols wave*64 + j*16 + q*4 .. +3); K-loop hides latency
    f32x4 ev[4];
#pragma unroll
    for (int j = 0; j < 4; ++j)
      ev[j] = *(const f32x4*)&E[(size_t)tokc * HID + wave * 64 + j * 16 + q * 4];

    i32x4 acc[4], accy;
#pragma unroll
    for (int j = 0; j < 4; ++j) acc[j] = i32x4{0, 0, 0, 0};
    accy = i32x4{0, 0, 0, 0};

    const int8_t* hr = &hbuf[cur][0][0];
    if (t > 0) {
#pragma unroll
      for (int kt = 0; kt < 8; ++kt) {
        const i32x4 a = *(const i32x4*)(hr + nn * HSTRB + kt * 64 + q * 16);
        // SWAPPED: W is the A operand, h the B operand => D[hid][batch]
        acc[0] = __builtin_amdgcn_mfma_i32_16x16x64_i8(wa[0][kt], a, acc[0], 0, 0, 0);
        acc[1] = __builtin_amdgcn_mfma_i32_16x16x64_i8(wa[1][kt], a, acc[1], 0, 0, 0);
        acc[2] = __builtin_amdgcn_mfma_i32_16x16x64_i8(wv[0][kt], a, acc[2], 0, 0, 0);
        acc[3] = __builtin_amdgcn_mfma_i32_16x16x64_i8(wv[1][kt], a, acc[3], 0, 0, 0);
        accy   = __builtin_amdgcn_mfma_i32_16x16x64_i8(wy[kt],    a, accy,   0, 0, 0);
      }
    }

    // epilogue: D row = q*4+r = hidden col offset, D col = nn = batch row.
    // h = tanh(acc*fq + ev); 4 i8 packed => one ds_write_b32 (2-way banks, free).
    int8_t* hw = &hbuf[cur ^ 1][0][0];
#pragma unroll
    for (int j = 0; j < 4; ++j) {
      uint32_t hp = 0;
#pragma unroll
      for (int r = 0; r < 4; ++r) {
        const float z = fmaf((float)acc[j][r], fq, ev[j][r]);
        const float h = fast_tanh(z);
        const int hi = __float2int_rn(h * 127.f);   // tanh bounded => no clamp needed
        hp |= ((uint32_t)hi & 0xffu) << (8 * r);
      }
      *(uint32_t*)(hw + nn * HSTRB + wave * 64 + j * 16 + q * 4) = hp;
    }
    if (t == SEQ - 1) {                   // exact fp32 h for the hT output only
#pragma unroll
      for (int j = 0; j < 4; ++j) {
        f32x4 hv;
#pragma unroll
        for (int r = 0; r < 4; ++r)
          hv[r] = fast_tanh(fmaf((float)acc[j][r], fq, ev[j][r]));
        *(f32x4*)&outH[(size_t)b * HID + wave * 64 + j * 16 + q * 4] = hv;
      }
    }

    // single per-step sync: drain own LDS ops (K-reads + h-writes), publish hw
    asm volatile("s_waitcnt lgkmcnt(0)\n\ts_barrier" ::: "memory");

    // y_{t-1}: 4 consecutive vocab cols => one float4 store; off the critical path
    if (t > 0) {
      f32x4 yv;
#pragma unroll
      for (int r = 0; r < 4; ++r) yv[r] = (float)accy[r] * fy + bo4[r];
      *(f32x4*)&out[((size_t)b * SEQ + (t - 1)) * VOCAB + wave * 16 + q * 4] = yv;
    }

    tokc = tokn;
    cur ^= 1;
  }

  // final y pass: hbuf[cur] holds h_{SEQ-1} (published by the loop's last barrier)
  {
    const int8_t* hr = &hbuf[cur][0][0];
    i32x4 accy = i32x4{0, 0, 0, 0};
#pragma unroll
    for (int kt = 0; kt < 8; ++kt) {
      const i32x4 a = *(const i32x4*)(hr + nn * HSTRB + kt * 64 + q * 16);
      accy = __builtin_amdgcn_mfma_i32_16x16x64_i8(wy[kt], a, accy, 0, 0, 0);
    }
    f32x4 yv;
#pragma unroll
    for (int r = 0; r < 4; ++r) yv[r] = (float)accy[r] * fy + bo4[r];
    *(f32x4*)&out[((size_t)b * SEQ + (SEQ - 1)) * VOCAB + wave * 16 + q * 4] = yv;
  }
}

extern "C" void kernel_launch(void* const* d_in, const int* in_sizes, int n_in,
                              void* d_out, int out_size, void* d_ws, size_t ws_size,
                              hipStream_t stream) {
  const int*   x    = (const int*)d_in[0];
  const float* emb  = (const float*)d_in[1];
  const float* W_ih = (const float*)d_in[2];
  const float* b_ih = (const float*)d_in[3];
  const float* W_hh = (const float*)d_in[4];
  const float* b_hh = (const float*)d_in[5];
  const float* W_ho = (const float*)d_in[6];
  const float* b_o  = (const float*)d_in[7];
  float* out = (float*)d_out;

  char* ws = (char*)d_ws;
  float*        E      = (float*)ws;                        // 256 KB
  uint4*        Wf8    = (uint4*)(ws + (256 << 10));        // 320 KB (40 nt x 8 x 1 KB)
  unsigned int* scu    = (unsigned int*)(ws + 589824);      // 2 scale slots
  const float*  scf    = (const float*)scu;

  hipMemsetAsync(scu, 0, 8, stream);   // ws is poisoned 0xAA every launch
  maxred_kernel<<<64, 256, 0, stream>>>(W_hh, HID * HID, scu + 0);
  maxred_kernel<<<16, 256, 0, stream>>>(W_ho, HID * VOCAB, scu + 1);
  eproj_kernel<<<VOCAB / 8, 512, 0, stream>>>(emb, W_ih, b_ih, b_hh, E);
  pack8_kernel<<<320, 64, 0, stream>>>(W_hh, W_ho, scf, Wf8);
  rnn_kernel<<<BATCH / BT, 512, 0, stream>>>(x, E, Wf8, scf, b_o, out,
                                             out + (size_t)BATCH * SEQ * VOCAB);
}

// Round 6
// 979.517 us; speedup vs baseline: 1.1012x; 1.1012x over previous
//
#include <hip/hip_runtime.h>
#include <cstdint>
#include <cstddef>

#define BATCH 256
#define SEQ   512
#define HID   512
#define VOCAB 128

#define BT     16              // batch rows per block
#define HSTRB  528             // h-buffer row stride in BYTES (512 + 16, 16B-aligned)

typedef __attribute__((ext_vector_type(4))) int   i32x4;
typedef __attribute__((ext_vector_type(4))) float f32x4;

// tanh(z) = 1 - 2/(e^{2z}+1); saturates correctly at +/-inf
static __device__ __forceinline__ float fast_tanh(float z) {
  float e = __expf(2.f * z);
  return 1.f - 2.f * __builtin_amdgcn_rcpf(e + 1.f);
}

// ---- abs-max reduction (for quantization scales) ----
__global__ void maxred_kernel(const float* __restrict__ src, int n,
                              unsigned int* __restrict__ dst) {
  float m = 0.f;
  for (int i = blockIdx.x * blockDim.x + threadIdx.x; i < n; i += gridDim.x * blockDim.x)
    m = fmaxf(m, fabsf(src[i]));
#pragma unroll
  for (int off = 32; off; off >>= 1)
    m = fmaxf(m, __shfl_down(m, off));
  if ((threadIdx.x & 63) == 0) atomicMax(dst, __float_as_uint(m));
}

// E[v][j] = sum_k emb[v][k]*W_ih[k][j] + b_ih[j] + b_hh[j]
__global__ __launch_bounds__(512) void eproj_kernel(const float* __restrict__ emb,
                                                    const float* __restrict__ W_ih,
                                                    const float* __restrict__ b_ih,
                                                    const float* __restrict__ b_hh,
                                                    float* __restrict__ E) {
  __shared__ float es[8][64];
  const int j = threadIdx.x;
  const int v0 = blockIdx.x * 8;
  float acc[8];
#pragma unroll
  for (int v = 0; v < 8; ++v) acc[v] = 0.f;
  for (int k0 = 0; k0 < HID; k0 += 64) {
    __syncthreads();
    es[j >> 6][j & 63] = emb[(size_t)(v0 + (j >> 6)) * HID + k0 + (j & 63)];
    __syncthreads();
#pragma unroll 8
    for (int kk = 0; kk < 64; ++kk) {
      const float w = W_ih[(size_t)(k0 + kk) * HID + j];
#pragma unroll
      for (int v = 0; v < 8; ++v) acc[v] += es[v][kk] * w;
    }
  }
  const float bias = b_ih[j] + b_hh[j];
#pragma unroll
  for (int v = 0; v < 8; ++v) E[(size_t)(v0 + v) * HID + j] = acc[v] + bias;
}

// Pack [W_hh | W_ho] (512 x 640) into i8 MFMA B-fragments for 16x16x64.
// Fragment f = nt*8+kt8: lane l holds 16 i8 = B[k = kt8*64 + (l>>4)*16 + i][n = nt*16 + (l&15)]
__global__ void pack8_kernel(const float* __restrict__ W_hh,
                             const float* __restrict__ W_ho,
                             const float* __restrict__ sc,   // sc[0]=max|W_hh|, sc[1]=max|W_ho|
                             uint4* __restrict__ Wf8) {
  const int f = blockIdx.x;            // 0..319 (40 nt * 8 kt8)
  const int nt = f >> 3, kt8 = f & 7;
  const int lane = threadIdx.x;
  const int q = lane >> 4, nn = lane & 15;
  const int n = nt * 16 + nn;
  const float inv = 127.f / ((nt < 32) ? sc[0] : sc[1]);
  union { int8_t b[16]; uint4 u; } val;
#pragma unroll
  for (int i = 0; i < 16; ++i) {
    const int k = kt8 * 64 + q * 16 + i;
    const float w = (n < HID) ? W_hh[(size_t)k * HID + n]
                              : W_ho[(size_t)k * VOCAB + (n - HID)];
    val.b[i] = (int8_t)__float2int_rn(w * inv);
  }
  Wf8[(size_t)f * 64 + lane] = val.u;
}

// Recurrence: h_t = tanh(E[x_t] + h_{t-1} @ W_hh), all-i8 MFMA.
// r0 structure (empirically best: 727 us) with ONE change: 16 waves (1024 thr)
// instead of 8. Each wave owns 2 n-tiles (nt = wave*2+j), weights fully AGPR-pinned
// (64 AGPRs). Per-wave K-loop MFMAs 32->16, epilogue 16->8 elements; 4 waves/SIMD
// (launch_bounds(1024,4), ~110 combined regs) doubles TLP for latency hiding.
// h kept as i8 in LDS (A-layout) + streamed to Hall (i8); separate ygemm pass.
__global__ __launch_bounds__(1024, 4)
void rnn_kernel(const int* __restrict__ x,
                const float* __restrict__ E,
                const uint4* __restrict__ Wf8,
                const float* __restrict__ sc,
                int8_t* __restrict__ Hall,
                float* __restrict__ outH) {
  __shared__ __align__(16) int8_t hbuf[BT][HSTRB];   // 8448 B

  const int tid = threadIdx.x;
  const int wave = tid >> 6, lane = tid & 63;        // wave 0..15
  const int q = lane >> 4, nn = lane & 15;
  const int r0 = blockIdx.x * BT;
  const float f = sc[0] * (1.f / (127.f * 127.f));   // s_w/127, uniform

  // 2 weight strips per wave (nt = wave*2+j), both pinned in AGPRs (64 regs)
  i32x4 wa[2][8];
  {
    const uint4* wb = Wf8 + lane;
#pragma unroll
    for (int j = 0; j < 2; ++j)
#pragma unroll
      for (int kt = 0; kt < 8; ++kt)
        wa[j][kt] = __builtin_bit_cast(i32x4, wb[(size_t)((wave * 2 + j) * 8 + kt) * 64]);
  }
#pragma unroll
  for (int j = 0; j < 2; ++j)
#pragma unroll
    for (int kt = 0; kt < 8; ++kt)
      asm volatile("" : "+a"(wa[j][kt]));

  // token prefetch for t=0
  int tokc[4];
#pragma unroll
  for (int r = 0; r < 4; ++r) tokc[r] = x[(size_t)(r0 + q * 4 + r) * SEQ + 0];

  for (int t = 0; t < SEQ; ++t) {
    int tokn[4];
    const int tn = (t + 1 < SEQ) ? t + 1 : t;
#pragma unroll
    for (int r = 0; r < 4; ++r) tokn[r] = x[(size_t)(r0 + q * 4 + r) * SEQ + tn];

    // E rows for this step's epilogue (K-loop hides the gather latency)
    float ev[2][4];
#pragma unroll
    for (int j = 0; j < 2; ++j)
#pragma unroll
      for (int r = 0; r < 4; ++r)
        ev[j][r] = E[(size_t)tokc[r] * HID + wave * 32 + j * 16 + nn];

    i32x4 acc[2];
#pragma unroll
    for (int j = 0; j < 2; ++j) acc[j] = i32x4{0, 0, 0, 0};

    if (t > 0) {
#pragma unroll
      for (int kt = 0; kt < 8; ++kt) {
        const i32x4 a = *(const i32x4*)&hbuf[nn][kt * 64 + q * 16];
        acc[0] = __builtin_amdgcn_mfma_i32_16x16x64_i8(a, wa[0][kt], acc[0], 0, 0, 0);
        acc[1] = __builtin_amdgcn_mfma_i32_16x16x64_i8(a, wa[1][kt], acc[1], 0, 0, 0);
      }
    }
    // read->write barrier (A-reads consumed at MFMA issue; no waitcnt needed)
    asm volatile("s_barrier" ::: "memory");

    // epilogue: h = tanh(f*acc + ev); D layout row m=q*4+r, col nn (verified)
#pragma unroll
    for (int j = 0; j < 2; ++j) {
      const int col = wave * 32 + j * 16 + nn;
#pragma unroll
      for (int r = 0; r < 4; ++r) {
        const int m = q * 4 + r;
        const float h = fast_tanh((float)acc[j][r] * f + ev[j][r]);
        const int hi = __float2int_rn(h * 127.f);
        hbuf[m][col] = (int8_t)hi;
        Hall[((size_t)(r0 + m) * SEQ + t) * HID + col] = (int8_t)hi;
        if (t == SEQ - 1) outH[(size_t)(r0 + m) * HID + col] = h;
      }
    }
    // write-publish barrier: drain LDS only, Hall stores keep pipelining
    asm volatile("s_waitcnt lgkmcnt(0)\n\ts_barrier" ::: "memory");

#pragma unroll
    for (int r = 0; r < 4; ++r) tokc[r] = tokn[r];
  }
}

// Y[b,s,:] = (f_hh_h * f_ho) * (h_i8 @ Who_i8) + b_o  — fully parallel, i8 MFMA.
__global__ __launch_bounds__(256)
void ygemm_kernel(const int8_t* __restrict__ Hall,
                  const uint4* __restrict__ Wf8,
                  const float* __restrict__ sc,
                  const float* __restrict__ b_o,
                  float* __restrict__ out) {
  const int tid = threadIdx.x;
  const int wave = tid >> 6, lane = tid & 63;
  const int q = lane >> 4, nn = lane & 15;
  const size_t row0 = (size_t)blockIdx.x * 64 + (size_t)wave * 16;
  const float f = sc[1] * (1.f / (127.f * 127.f));
  i32x4 acc[8];
#pragma unroll
  for (int i = 0; i < 8; ++i) acc[i] = i32x4{0, 0, 0, 0};
  const int8_t* ha = Hall + (row0 + nn) * HID + q * 16;
  const uint4* wb = Wf8 + lane;
#pragma unroll
  for (int kt = 0; kt < 8; ++kt) {
    const i32x4 a = *(const i32x4*)(ha + kt * 64);
#pragma unroll
    for (int nt = 0; nt < 8; ++nt) {
      const i32x4 b = __builtin_bit_cast(i32x4, wb[(size_t)((32 + nt) * 8 + kt) * 64]);
      acc[nt] = __builtin_amdgcn_mfma_i32_16x16x64_i8(a, b, acc[nt], 0, 0, 0);
    }
  }
#pragma unroll
  for (int nt = 0; nt < 8; ++nt) {
    const float bo = b_o[nt * 16 + nn];
#pragma unroll
    for (int r = 0; r < 4; ++r)
      out[(row0 + q * 4 + r) * VOCAB + nt * 16 + nn] = (float)acc[nt][r] * f + bo;
  }
}

extern "C" void kernel_launch(void* const* d_in, const int* in_sizes, int n_in,
                              void* d_out, int out_size, void* d_ws, size_t ws_size,
                              hipStream_t stream) {
  const int*   x    = (const int*)d_in[0];
  const float* emb  = (const float*)d_in[1];
  const float* W_ih = (const float*)d_in[2];
  const float* b_ih = (const float*)d_in[3];
  const float* W_hh = (const float*)d_in[4];
  const float* b_hh = (const float*)d_in[5];
  const float* W_ho = (const float*)d_in[6];
  const float* b_o  = (const float*)d_in[7];
  float* out = (float*)d_out;

  char* ws = (char*)d_ws;
  float*        E      = (float*)ws;                        // 256 KB
  uint4*        Wf8    = (uint4*)(ws + (256 << 10));        // 320 KB (40 nt x 8 x 1 KB)
  unsigned int* scu    = (unsigned int*)(ws + 589824);      // 2 scale slots
  const float*  scf    = (const float*)scu;
  int8_t*       Hall   = (int8_t*)(ws + (1 << 20));         // 64 MB i8

  hipMemsetAsync(scu, 0, 8, stream);   // ws is poisoned 0xAA every launch
  maxred_kernel<<<64, 256, 0, stream>>>(W_hh, HID * HID, scu + 0);
  maxred_kernel<<<16, 256, 0, stream>>>(W_ho, HID * VOCAB, scu + 1);
  eproj_kernel<<<VOCAB / 8, 512, 0, stream>>>(emb, W_ih, b_ih, b_hh, E);
  pack8_kernel<<<320, 64, 0, stream>>>(W_hh, W_ho, scf, Wf8);
  rnn_kernel<<<16, 1024, 0, stream>>>(x, E, Wf8, scf, Hall,
                                      out + (size_t)BATCH * SEQ * VOCAB);
  ygemm_kernel<<<(BATCH * SEQ) / 64, 256, 0, stream>>>(Hall, Wf8, scf, b_o, out);
}

// Round 8
// 886.607 us; speedup vs baseline: 1.2166x; 1.1048x over previous
//
#include <hip/hip_runtime.h>
#include <cstdint>
#include <cstddef>

#define BATCH 256
#define SEQ   512
#define HID   512
#define VOCAB 128

#define BT     16              // batch rows per block
#define HSTRB  528             // h-buffer row stride in BYTES (512 + 16, 16B-aligned)
#define LOG2E2 2.88539008177793f   // 2*log2(e): e^{2z} = 2^(z*LOG2E2), baked into E and fq

typedef __attribute__((ext_vector_type(4))) int   i32x4;
typedef __attribute__((ext_vector_type(4))) float f32x4;

// ---- abs-max reduction (for quantization scales) ----
__global__ void maxred_kernel(const float* __restrict__ src, int n,
                              unsigned int* __restrict__ dst) {
  float m = 0.f;
  for (int i = blockIdx.x * blockDim.x + threadIdx.x; i < n; i += gridDim.x * blockDim.x)
    m = fmaxf(m, fabsf(src[i]));
#pragma unroll
  for (int off = 32; off; off >>= 1)
    m = fmaxf(m, __shfl_down(m, off));
  if ((threadIdx.x & 63) == 0) atomicMax(dst, __float_as_uint(m));
}

// E'[v][j] = (sum_k emb[v][k]*W_ih[k][j] + b_ih[j] + b_hh[j]) * 2*log2(e)
// (folds the e^{2z} = 2^(z*2log2e) scale so the recurrence epilogue is 1 fma + v_exp)
__global__ __launch_bounds__(512) void eproj_kernel(const float* __restrict__ emb,
                                                    const float* __restrict__ W_ih,
                                                    const float* __restrict__ b_ih,
                                                    const float* __restrict__ b_hh,
                                                    float* __restrict__ E) {
  __shared__ float es[8][64];
  const int j = threadIdx.x;
  const int v0 = blockIdx.x * 8;
  float acc[8];
#pragma unroll
  for (int v = 0; v < 8; ++v) acc[v] = 0.f;
  for (int k0 = 0; k0 < HID; k0 += 64) {
    __syncthreads();
    es[j >> 6][j & 63] = emb[(size_t)(v0 + (j >> 6)) * HID + k0 + (j & 63)];
    __syncthreads();
#pragma unroll 8
    for (int kk = 0; kk < 64; ++kk) {
      const float w = W_ih[(size_t)(k0 + kk) * HID + j];
#pragma unroll
      for (int v = 0; v < 8; ++v) acc[v] += es[v][kk] * w;
    }
  }
  const float bias = b_ih[j] + b_hh[j];
#pragma unroll
  for (int v = 0; v < 8; ++v)
    E[(size_t)(v0 + v) * HID + j] = (acc[v] + bias) * LOG2E2;
}

// Pack [W_hh | W_ho] (512 x 640) into i8 MFMA B-fragments for 16x16x64.
// Fragment f = nt*8+kt8: lane l holds 16 i8 = B[k = kt8*64 + (l>>4)*16 + i][n = nt*16 + (l&15)]
__global__ void pack8_kernel(const float* __restrict__ W_hh,
                             const float* __restrict__ W_ho,
                             const float* __restrict__ sc,   // sc[0]=max|W_hh|, sc[1]=max|W_ho|
                             uint4* __restrict__ Wf8) {
  const int f = blockIdx.x;            // 0..319 (40 nt * 8 kt8)
  const int nt = f >> 3, kt8 = f & 7;
  const int lane = threadIdx.x;
  const int q = lane >> 4, nn = lane & 15;
  const int n = nt * 16 + nn;
  const float inv = 127.f / ((nt < 32) ? sc[0] : sc[1]);
  union { int8_t b[16]; uint4 u; } val;
#pragma unroll
  for (int i = 0; i < 16; ++i) {
    const int k = kt8 * 64 + q * 16 + i;
    const float w = (n < HID) ? W_hh[(size_t)k * HID + n]
                              : W_ho[(size_t)k * VOCAB + (n - HID)];
    val.b[i] = (int8_t)__float2int_rn(w * inv);
  }
  Wf8[(size_t)f * 64 + lane] = val.u;
}

// Recurrence: h_t = tanh(E[x_t] + h_{t-1} @ W_hh), all-i8 MFMA.
// r0 structure (empirically best) with TWO changes:
//  1. hbuf double-buffered -> ONE barrier/step (was two). Within a step, wave B's
//     K-loop MFMAs overlap wave A's epilogue VALU (reads hit buf[cur], writes go to
//     buf[cur^1], disjoint; the lgkmcnt(0)+barrier publishes the writes).
//  2. Folded tanh: z' = acc*fq' + E'  (E', fq' carry 2*log2e); e=v_exp(z');
//     r=rcp(e+1); h127 = 127 - 254*r. Saves 3 VALU ops/element vs r0.
// 16 blocks x 512 threads (8 waves, 2/SIMD); weights register-pinned (2 AGPR strips
// + 2 VGPR strips/wave). h i8 in LDS + streamed to Hall; separate ygemm pass.
__global__ __launch_bounds__(512, 2)
void rnn_kernel(const int* __restrict__ x,
                const float* __restrict__ E,
                const uint4* __restrict__ Wf8,
                const float* __restrict__ sc,
                int8_t* __restrict__ Hall,
                float* __restrict__ outH) {
  __shared__ __align__(16) int8_t hbuf[2][BT][HSTRB];   // 16.9 KB double-buffered

  const int tid = threadIdx.x;
  const int wave = tid >> 6, lane = tid & 63;
  const int q = lane >> 4, nn = lane & 15;
  const int r0 = blockIdx.x * BT;
  const float fq = sc[0] * (LOG2E2 / (127.f * 127.f));  // acc -> 2log2e * preact

  // 4 weight strips per wave (nt = wave*4+j): j<2 in AGPR, j>=2 in VGPR; pinned.
  i32x4 wa[2][8], wv[2][8];
  {
    const uint4* wb = Wf8 + lane;
#pragma unroll
    for (int j = 0; j < 2; ++j)
#pragma unroll
      for (int kt = 0; kt < 8; ++kt)
        wa[j][kt] = __builtin_bit_cast(i32x4, wb[(size_t)((wave * 4 + j) * 8 + kt) * 64]);
#pragma unroll
    for (int j = 0; j < 2; ++j)
#pragma unroll
      for (int kt = 0; kt < 8; ++kt)
        wv[j][kt] = __builtin_bit_cast(i32x4, wb[(size_t)((wave * 4 + 2 + j) * 8 + kt) * 64]);
  }
#pragma unroll
  for (int j = 0; j < 2; ++j)
#pragma unroll
    for (int kt = 0; kt < 8; ++kt)
      asm volatile("" : "+a"(wa[j][kt]));
#pragma unroll
  for (int j = 0; j < 2; ++j)
#pragma unroll
    for (int kt = 0; kt < 8; ++kt)
      asm volatile("" : "+v"(wv[j][kt]));

  // token prefetch for t=0
  int tokc[4];
#pragma unroll
  for (int r = 0; r < 4; ++r) tokc[r] = x[(size_t)(r0 + q * 4 + r) * SEQ + 0];

  int cur = 0;
  for (int t = 0; t < SEQ; ++t) {
    int tokn[4];
    const int tn = (t + 1 < SEQ) ? t + 1 : t;
#pragma unroll
    for (int r = 0; r < 4; ++r) tokn[r] = x[(size_t)(r0 + q * 4 + r) * SEQ + tn];

    // E' rows for this step's epilogue (K-loop hides the gather latency)
    float ev[4][4];
#pragma unroll
    for (int j = 0; j < 4; ++j)
#pragma unroll
      for (int r = 0; r < 4; ++r)
        ev[j][r] = E[(size_t)tokc[r] * HID + wave * 64 + j * 16 + nn];

    i32x4 acc[4];
#pragma unroll
    for (int j = 0; j < 4; ++j) acc[j] = i32x4{0, 0, 0, 0};

    if (t > 0) {
#pragma unroll
      for (int kt = 0; kt < 8; ++kt) {
        const i32x4 a = *(const i32x4*)&hbuf[cur][nn][kt * 64 + q * 16];
        acc[0] = __builtin_amdgcn_mfma_i32_16x16x64_i8(a, wa[0][kt], acc[0], 0, 0, 0);
        acc[1] = __builtin_amdgcn_mfma_i32_16x16x64_i8(a, wa[1][kt], acc[1], 0, 0, 0);
        acc[2] = __builtin_amdgcn_mfma_i32_16x16x64_i8(a, wv[0][kt], acc[2], 0, 0, 0);
        acc[3] = __builtin_amdgcn_mfma_i32_16x16x64_i8(a, wv[1][kt], acc[3], 0, 0, 0);
      }
    }
    // NO barrier here: epilogue writes go to buf[cur^1] (disjoint from reads of buf[cur])

    // epilogue: z' = acc*fq + ev' (carries 2log2e); e=2^z'; r=1/(e+1);
    // h127 = 127 - 254r;  D layout row m=q*4+r, col nn (verified)
#pragma unroll
    for (int j = 0; j < 4; ++j) {
      const int col = wave * 64 + j * 16 + nn;
#pragma unroll
      for (int r = 0; r < 4; ++r) {
        const int m = q * 4 + r;
        const float zp = fmaf((float)acc[j][r], fq, ev[j][r]);
        float e;
        asm("v_exp_f32 %0, %1" : "=v"(e) : "v"(zp));     // e = 2^zp = e^{2z}
        const float rr = __builtin_amdgcn_rcpf(e + 1.f);
        const int hi = __float2int_rn(fmaf(-254.f, rr, 127.f));
        hbuf[cur ^ 1][m][col] = (int8_t)hi;
        Hall[((size_t)(r0 + m) * SEQ + t) * HID + col] = (int8_t)hi;
        if (t == SEQ - 1)
          outH[(size_t)(r0 + m) * HID + col] = fmaf(-2.f, rr, 1.f);  // exact tanh value
      }
    }
    // single per-step sync: drain this wave's LDS reads+writes, publish buf[cur^1]
    asm volatile("s_waitcnt lgkmcnt(0)\n\ts_barrier" ::: "memory");

#pragma unroll
    for (int r = 0; r < 4; ++r) tokc[r] = tokn[r];
    cur ^= 1;
  }
}

// Y[b,s,:] = (f_hh_h * f_ho) * (h_i8 @ Who_i8) + b_o  — fully parallel, i8 MFMA.
__global__ __launch_bounds__(256)
void ygemm_kernel(const int8_t* __restrict__ Hall,
                  const uint4* __restrict__ Wf8,
                  const float* __restrict__ sc,
                  const float* __restrict__ b_o,
                  float* __restrict__ out) {
  const int tid = threadIdx.x;
  const int wave = tid >> 6, lane = tid & 63;
  const int q = lane >> 4, nn = lane & 15;
  const size_t row0 = (size_t)blockIdx.x * 64 + (size_t)wave * 16;
  const float f = sc[1] * (1.f / (127.f * 127.f));
  i32x4 acc[8];
#pragma unroll
  for (int i = 0; i < 8; ++i) acc[i] = i32x4{0, 0, 0, 0};
  const int8_t* ha = Hall + (row0 + nn) * HID + q * 16;
  const uint4* wb = Wf8 + lane;
#pragma unroll
  for (int kt = 0; kt < 8; ++kt) {
    const i32x4 a = *(const i32x4*)(ha + kt * 64);
#pragma unroll
    for (int nt = 0; nt < 8; ++nt) {
      const i32x4 b = __builtin_bit_cast(i32x4, wb[(size_t)((32 + nt) * 8 + kt) * 64]);
      acc[nt] = __builtin_amdgcn_mfma_i32_16x16x64_i8(a, b, acc[nt], 0, 0, 0);
    }
  }
#pragma unroll
  for (int nt = 0; nt < 8; ++nt) {
    const float bo = b_o[nt * 16 + nn];
#pragma unroll
    for (int r = 0; r < 4; ++r)
      out[(row0 + q * 4 + r) * VOCAB + nt * 16 + nn] = (float)acc[nt][r] * f + bo;
  }
}

extern "C" void kernel_launch(void* const* d_in, const int* in_sizes, int n_in,
                              void* d_out, int out_size, void* d_ws, size_t ws_size,
                              hipStream_t stream) {
  const int*   x    = (const int*)d_in[0];
  const float* emb  = (const float*)d_in[1];
  const float* W_ih = (const float*)d_in[2];
  const float* b_ih = (const float*)d_in[3];
  const float* W_hh = (const float*)d_in[4];
  const float* b_hh = (const float*)d_in[5];
  const float* W_ho = (const float*)d_in[6];
  const float* b_o  = (const float*)d_in[7];
  float* out = (float*)d_out;

  char* ws = (char*)d_ws;
  float*        E      = (float*)ws;                        // 256 KB (E', 2log2e-scaled)
  uint4*        Wf8    = (uint4*)(ws + (256 << 10));        // 320 KB (40 nt x 8 x 1 KB)
  unsigned int* scu    = (unsigned int*)(ws + 589824);      // 2 scale slots
  const float*  scf    = (const float*)scu;
  int8_t*       Hall   = (int8_t*)(ws + (1 << 20));         // 64 MB i8

  hipMemsetAsync(scu, 0, 8, stream);   // ws is poisoned 0xAA every launch
  maxred_kernel<<<64, 256, 0, stream>>>(W_hh, HID * HID, scu + 0);
  maxred_kernel<<<16, 256, 0, stream>>>(W_ho, HID * VOCAB, scu + 1);
  eproj_kernel<<<VOCAB / 8, 512, 0, stream>>>(emb, W_ih, b_ih, b_hh, E);
  pack8_kernel<<<320, 64, 0, stream>>>(W_hh, W_ho, scf, Wf8);
  rnn_kernel<<<16, 512, 0, stream>>>(x, E, Wf8, scf, Hall,
                                     out + (size_t)BATCH * SEQ * VOCAB);
  ygemm_kernel<<<(BATCH * SEQ) / 64, 256, 0, stream>>>(Hall, Wf8, scf, b_o, out);
}